// Round 1
// 669.518 us; speedup vs baseline: 1.0307x; 1.0307x over previous
//
#include <hip/hip_runtime.h>
#include <hip/hip_fp16.h>
#include <cstdint>
#include <cstddef>

#define HIDDEN 2048
#define INTER  4096
#define EPSQ   1e-5f

typedef int v4i __attribute__((ext_vector_type(4)));

__device__ __forceinline__ void async_ld16(const void* g, void* l) {
  __builtin_amdgcn_global_load_lds((const __attribute__((address_space(1))) void*)g,
                                   (__attribute__((address_space(3))) void*)l, 16, 0, 0);
}

#define BAR()   __builtin_amdgcn_s_barrier()
#define LGKM0() asm volatile("s_waitcnt lgkmcnt(0)" ::: "memory")
#define VMC(n)  asm volatile("s_waitcnt vmcnt(" #n ")" ::: "memory")

// ---------------- absmean reduction (f64 accumulate, atomic combine) ----------------
__global__ void absmean_kernel(const float* __restrict__ w, size_t n4, double* __restrict__ out) {
  double s = 0.0;
  const float4* w4 = (const float4*)w;
  for (size_t i = blockIdx.x * (size_t)blockDim.x + threadIdx.x; i < n4;
       i += (size_t)gridDim.x * blockDim.x) {
    float4 v = w4[i];
    s += (double)fabsf(v.x) + (double)fabsf(v.y) + (double)fabsf(v.z) + (double)fabsf(v.w);
  }
  #pragma unroll
  for (int o = 32; o; o >>= 1) s += __shfl_down(s, o);
  __shared__ double red[4];
  if ((threadIdx.x & 63) == 0) red[threadIdx.x >> 6] = s;
  __syncthreads();
  if (threadIdx.x == 0) atomicAdd(out, red[0] + red[1] + red[2] + red[3]);
}

// ---------------- weight ternarization: q = clip(round(w/scale), -1, 1) ----------------
__global__ void quantw_kernel(const float* __restrict__ w, size_t n4,
                              const double* __restrict__ sum, double invcnt,
                              int8_t* __restrict__ q) {
  const float scale = (float)fmax(sum[0] * invcnt, (double)EPSQ);
  const float4* w4 = (const float4*)w;
  char4* q4 = (char4*)q;
  for (size_t i = blockIdx.x * (size_t)blockDim.x + threadIdx.x; i < n4;
       i += (size_t)gridDim.x * blockDim.x) {
    float4 v = w4[i];
    char4 c;
    c.x = (signed char)fmaxf(-1.f, fminf(1.f, rintf(v.x / scale)));
    c.y = (signed char)fmaxf(-1.f, fminf(1.f, rintf(v.y / scale)));
    c.z = (signed char)fmaxf(-1.f, fminf(1.f, rintf(v.z / scale)));
    c.w = (signed char)fmaxf(-1.f, fminf(1.f, rintf(v.w / scale)));
    q4[i] = c;
  }
}

// ---------------- FWHT: one wave per token, H_N = H_E(regs) (x) H_64(lanes) ----------------
template <int LOGN, bool HALF_IN>
__global__ void __launch_bounds__(256) fwht_quant_kernel(const void* __restrict__ Xv,
                                                         int8_t* __restrict__ Q,
                                                         float* __restrict__ invs) {
  constexpr int N = 1 << LOGN;
  constexpr int E = N / 64;                     // 32 (2048) or 64 (4096) regs/lane
  const int lane = threadIdx.x & 63;
  const size_t t = (size_t)blockIdx.x * 4 + (threadIdx.x >> 6);

  float r[E];
  if constexpr (HALF_IN) {
    const int4* xp = (const int4*)((const __half*)Xv + t * (size_t)N + lane * E);
    #pragma unroll
    for (int u = 0; u < E / 8; ++u) {
      alignas(16) __half hb[8];
      *(int4*)hb = xp[u];
      #pragma unroll
      for (int j = 0; j < 8; ++j) r[u * 8 + j] = __half2float(hb[j]);
    }
  } else {
    const float4* xp = (const float4*)((const float*)Xv + t * (size_t)N + lane * E);
    #pragma unroll
    for (int u = 0; u < E / 4; ++u) {
      float4 v = xp[u];
      r[u * 4 + 0] = v.x; r[u * 4 + 1] = v.y; r[u * 4 + 2] = v.z; r[u * 4 + 3] = v.w;
    }
  }

  #pragma unroll
  for (int m = 1; m < E; m <<= 1) {
    #pragma unroll
    for (int e = 0; e < E; ++e) {
      if (!(e & m)) {
        float a = r[e], b = r[e | m];
        r[e] = a + b;
        r[e | m] = a - b;
      }
    }
  }
  #pragma unroll
  for (int m = 1; m < 64; m <<= 1) {
    const float sgn = (lane & m) ? -1.f : 1.f;
    #pragma unroll
    for (int e = 0; e < E; ++e) {
      float w = __shfl_xor(r[e], m, 64);
      r[e] = fmaf(r[e], sgn, w);
    }
  }

  float mx = 0.f;
  #pragma unroll
  for (int e = 0; e < E; ++e) mx = fmaxf(mx, fabsf(r[e]));
  #pragma unroll
  for (int m = 1; m < 64; m <<= 1) mx = fmaxf(mx, __shfl_xor(mx, m, 64));

  constexpr float c = (LOGN == 11) ? 0.022097086912079608f : 0.015625f;  // 1/sqrt(N)
  mx = fmaxf(mx * c, EPSQ);
  const float sc = 127.0f * c / mx;
  if (lane == 0) invs[t] = mx * (1.0f / 127.0f);

  alignas(16) int8_t qv[E];
  #pragma unroll
  for (int e = 0; e < E; ++e) {
    float q = rintf(r[e] * sc);
    q = fmaxf(-127.f, fminf(127.f, q));
    qv[e] = (int8_t)q;
  }
  int8_t* qp = Q + t * (size_t)N + lane * E;
  #pragma unroll
  for (int u = 0; u < E / 16; ++u) ((int4*)qp)[u] = ((const int4*)qv)[u];
}

// ---------------- int8 GEMM, 256x256 tile, 8-phase schedule (T1+T2+T3/T4+T5) --------
// 8 waves (2M x 4N), each wave a 128x64 output via 8x4 mfma_i32_16x16x64_i8 frags.
// BK = 128 bytes/K-tile; 2 K-tiles per loop iteration; 8 phases of
// { ds_read subtile ; stage 1 half-tile ; barrier ; lgkmcnt(0) ; 16 MFMA ; barrier }.
// LDS 128 KiB = 2 dbuf x (A,B) x 2 halves x 128 rows x 128 B, XOR-swizzled
// (linear gload_lds dest + inverse-swizzled global source + swizzled ds_read).
// vmcnt is counted (2) at phases 4/8 only: buf1 halves staged at {ph8',ph1,ph2,ph3}
// land by ph4's vmcnt(2); buf0' halves {ph4..ph7} land by ph8's vmcnt(2). Each
// buffer's stage slot opens after the barrier following its last ds_read (12/4/8/0).
template <bool RELU2, typename TOUT>
__global__ __launch_bounds__(512, 2)
void gemm_i8_8ph(const int8_t* __restrict__ A, const int8_t* __restrict__ B,
                 TOUT* __restrict__ C, const float* __restrict__ invs,
                 const double* __restrict__ wsum, double invcnt,
                 int N, int K) {
  __shared__ int8_t As[2 * 2 * 128 * 128];
  __shared__ int8_t Bs[2 * 2 * 128 * 128];

  // T1: XCD-aware chunked swizzle (nwg % 8 == 0 for all launches here)
  const int GX = N >> 8;
  const int nwg = gridDim.x;
  int wg = blockIdx.x;
  wg = (wg & 7) * (nwg >> 3) + (wg >> 3);
  const int bx = wg % GX;
  const int by = wg / GX;
  const int m0 = by * 256, n0 = bx * 256;

  const int t = threadIdx.x;
  const int lane = t & 63;
  const int wave = t >> 6;
  const int wr = wave >> 2;  // 0..1 (M)
  const int wc = wave & 3;   // 0..3 (N)

  // ---- staging: global source pre-swizzled, LDS dest linear (rule: both-or-neither)
  const int row0 = t >> 3;                                  // 0..63
  const int colsw = ((t & 7) * 16) ^ ((row0 & 7) << 4);
  const int8_t* gA0 = A + (size_t)(m0 + row0) * K + colsw;
  const int8_t* gA1 = gA0 + (size_t)128 * K;
  const int8_t* gB0 = B + (size_t)(n0 + row0) * K + colsw;
  const int8_t* gB1 = gB0 + (size_t)128 * K;
  const size_t rstep = (size_t)64 * K;

  auto SA = [&](int bf, int hf, int kt) {
    const int8_t* g = (hf ? gA1 : gA0) + (size_t)kt * 128;
    int8_t* l = As + bf * 32768 + hf * 16384 + t * 16;
    async_ld16(g, l);
    async_ld16(g + rstep, l + 8192);
  };
  auto SB = [&](int bf, int hf, int kt) {
    const int8_t* g = (hf ? gB1 : gB0) + (size_t)kt * 128;
    int8_t* l = Bs + bf * 32768 + hf * 16384 + t * 16;
    async_ld16(g, l);
    async_ld16(g + rstep, l + 8192);
  };

  // ---- swizzled ds_read addressing: row&7 == lane&7 for every fragment row
  const int csw0 = ((lane >> 4) * 16) ^ ((lane & 7) << 4);        // kk = 0
  const int csw1 = (64 + (lane >> 4) * 16) ^ ((lane & 7) << 4);   // kk = 1
  const int8_t* pA0 = As + wr * 16384 + (lane & 15) * 128;
  const int8_t* pB0 = Bs + (wc >> 1) * 16384 + ((wc & 1) * 64 + (lane & 15)) * 128;

  v4i acc[8][4] = {};
  v4i a[4][2], b[4][2];

  auto RDA = [&](int bf, int m4) {
    const int8_t* p = pA0 + bf * 32768 + m4 * 8192;
    #pragma unroll
    for (int mt = 0; mt < 4; ++mt) {
      a[mt][0] = *(const v4i*)(p + mt * 2048 + csw0);
      a[mt][1] = *(const v4i*)(p + mt * 2048 + csw1);
    }
  };
  auto RDB = [&](int bf, int n2) {
    const int8_t* p = pB0 + bf * 32768 + n2 * 4096;
    #pragma unroll
    for (int nt = 0; nt < 2; ++nt) {
      b[n2 * 2 + nt][0] = *(const v4i*)(p + nt * 2048 + csw0);
      b[n2 * 2 + nt][1] = *(const v4i*)(p + nt * 2048 + csw1);
    }
  };
  auto MM = [&](int m4, int n2) {   // T5: setprio around the 16-MFMA cluster
    __builtin_amdgcn_s_setprio(1);
    #pragma unroll
    for (int mt = 0; mt < 4; ++mt)
      #pragma unroll
      for (int nt = 0; nt < 2; ++nt) {
        v4i* c = &acc[m4 * 4 + mt][n2 * 2 + nt];
        *c = __builtin_amdgcn_mfma_i32_16x16x64_i8(a[mt][0], b[n2 * 2 + nt][0], *c, 0, 0, 0);
        *c = __builtin_amdgcn_mfma_i32_16x16x64_i8(a[mt][1], b[n2 * 2 + nt][1], *c, 0, 0, 0);
      }
    __builtin_amdgcn_s_setprio(0);
  };

  const int NIT = K >> 8;  // 2 K-tiles (256 bytes of K) per iteration; NIT >= 2 here

  // prologue: tile0 -> buf0 (4 halves), tile1 half A0 -> buf1; wait for buf0
  SA(0, 0, 0); SA(0, 1, 0); SB(0, 0, 0); SB(0, 1, 0);
  SA(1, 0, 1);
  VMC(2);
  BAR();

  for (int it = 0; it < NIT; ++it) {
    const int kt1 = 2 * it + 1, kt2 = 2 * it + 2, kt3 = 2 * it + 3;
    const bool more = it < NIT - 1;

    // ph1: buf0 reads A(mt0-3) + B(nt0-1); stage buf1.A1 (tile kt1)
    RDA(0, 0); RDB(0, 0);
    SA(1, 1, kt1);
    BAR(); LGKM0(); MM(0, 0); BAR();

    // ph2: buf0 B(nt2-3); stage buf1.B0
    RDB(0, 1);
    SB(1, 0, kt1);
    BAR(); LGKM0(); MM(0, 1); BAR();

    // ph3: buf0 A(mt4-7) (last buf0 read); stage buf1.B1
    RDA(0, 1);
    SB(1, 1, kt1);
    BAR(); LGKM0(); MM(1, 0); BAR();

    // ph4: stage buf0.A0 (tile kt2); counted vmcnt -> buf1 fully landed
    if (more) { SA(0, 0, kt2); VMC(2); } else { VMC(0); }
    BAR(); MM(1, 1); BAR();

    // ph5: buf1 reads A(mt0-3) + B(nt0-1); stage buf0.A1
    RDA(1, 0); RDB(1, 0);
    if (more) SA(0, 1, kt2);
    BAR(); LGKM0(); MM(0, 0); BAR();

    // ph6: buf1 B(nt2-3); stage buf0.B0
    RDB(1, 1);
    if (more) SB(0, 0, kt2);
    BAR(); LGKM0(); MM(0, 1); BAR();

    // ph7: buf1 A(mt4-7) (last buf1 read); stage buf0.B1
    RDA(1, 1);
    if (more) SB(0, 1, kt2);
    BAR(); LGKM0(); MM(1, 0); BAR();

    // ph8: stage buf1.A0 (tile kt3); counted vmcnt -> buf0' fully landed
    if (more) { SA(1, 0, kt3); VMC(2); }
    BAR(); MM(1, 1); BAR();
  }

  // ---- epilogue: C/D layout (16x16): col = lane&15, row = (lane>>4)*4 + reg
  const float wscale = (float)fmax(wsum[0] * invcnt, (double)EPSQ);
  const int crow_base = m0 + wr * 128 + (lane >> 4) * 4;
  const int ccol_base = n0 + wc * 64 + (lane & 15);
  #pragma unroll
  for (int mt = 0; mt < 8; ++mt) {
    const int trow = crow_base + mt * 16;
    float fr[4];
    #pragma unroll
    for (int r = 0; r < 4; ++r) fr[r] = wscale * invs[trow + r];
    #pragma unroll
    for (int nt = 0; nt < 4; ++nt) {
      const int col = ccol_base + nt * 16;
      #pragma unroll
      for (int r = 0; r < 4; ++r) {
        float v = (float)acc[mt][nt][r] * fr[r];
        if (RELU2) v = v > 0.f ? v * v : 0.f;
        if constexpr (sizeof(TOUT) == 2)
          C[(size_t)(trow + r) * N + col] = __float2half(v);
        else
          C[(size_t)(trow + r) * N + col] = v;
      }
    }
  }
}

extern "C" void kernel_launch(void* const* d_in, const int* in_sizes, int n_in,
                              void* d_out, int out_size, void* d_ws, size_t ws_size,
                              hipStream_t stream) {
  const float* x      = (const float*)d_in[0];   // (4,4096,2048)
  const float* w_up   = (const float*)d_in[1];   // (4096,2048)
  const float* w_down = (const float*)d_in[2];   // (2048,4096)
  float* out = (float*)d_out;

  const int T = in_sizes[0] / HIDDEN;            // 16384 tokens
  const size_t WN = (size_t)INTER * HIDDEN;      // 8388608 weights per matrix

  char* ws = (char*)d_ws;
  double* sums   = (double*)ws;                                   // [2]
  float* invs1   = (float*)(ws + 256);                            // [T]
  float* invs2   = (float*)(ws + 256 + 65536);                    // [T]
  int8_t* wq_up  = (int8_t*)(ws + 131328);                        // 8 MB
  int8_t* wq_dn  = wq_up + WN;                                    // 8 MB
  int8_t* a8_1   = wq_dn + WN;                                    // T*2048
  int8_t* a8_2   = a8_1 + (size_t)T * HIDDEN;                     // T*4096
  __half* h      = (__half*)(a8_2 + (size_t)T * INTER);           // T*4096 fp16

  const double invcnt = 1.0 / (double)WN;

  hipMemsetAsync(sums, 0, 256, stream);
  absmean_kernel<<<1024, 256, 0, stream>>>(w_up, WN / 4, sums + 0);
  absmean_kernel<<<1024, 256, 0, stream>>>(w_down, WN / 4, sums + 1);
  quantw_kernel<<<2048, 256, 0, stream>>>(w_up, WN / 4, sums + 0, invcnt, wq_up);
  quantw_kernel<<<2048, 256, 0, stream>>>(w_down, WN / 4, sums + 1, invcnt, wq_dn);

  fwht_quant_kernel<11, false><<<T / 4, 256, 0, stream>>>(x, a8_1, invs1);
  gemm_i8_8ph<true, __half><<<(T / 256) * (INTER / 256), 512, 0, stream>>>(
      a8_1, wq_up, h, invs1, sums + 0, invcnt, INTER, HIDDEN);
  fwht_quant_kernel<12, true><<<T / 4, 256, 0, stream>>>(h, a8_2, invs2);
  gemm_i8_8ph<false, float><<<(T / 256) * (HIDDEN / 256), 512, 0, stream>>>(
      a8_2, wq_dn, out, invs2, sums + 1, invcnt, HIDDEN, INTER);
}

// Round 3
// 654.837 us; speedup vs baseline: 1.0538x; 1.0224x over previous
//
#include <hip/hip_runtime.h>
#include <hip/hip_fp16.h>
#include <cstdint>
#include <cstddef>

#define HIDDEN 2048
#define INTER  4096
#define EPSQ   1e-5f

typedef int v4i __attribute__((ext_vector_type(4)));

__device__ __forceinline__ void async_ld16(const void* g, void* l) {
  __builtin_amdgcn_global_load_lds((const __attribute__((address_space(1))) void*)g,
                                   (__attribute__((address_space(3))) void*)l, 16, 0, 0);
}

#define BAR()   __builtin_amdgcn_s_barrier()
#define VMC(n)  asm volatile("s_waitcnt vmcnt(" #n ")" ::: "memory")

// ---------------- absmean reduction (f64 accumulate, atomic combine) ----------------
__global__ void absmean_kernel(const float* __restrict__ w, size_t n4, double* __restrict__ out) {
  double s = 0.0;
  const float4* w4 = (const float4*)w;
  for (size_t i = blockIdx.x * (size_t)blockDim.x + threadIdx.x; i < n4;
       i += (size_t)gridDim.x * blockDim.x) {
    float4 v = w4[i];
    s += (double)fabsf(v.x) + (double)fabsf(v.y) + (double)fabsf(v.z) + (double)fabsf(v.w);
  }
  #pragma unroll
  for (int o = 32; o; o >>= 1) s += __shfl_down(s, o);
  __shared__ double red[4];
  if ((threadIdx.x & 63) == 0) red[threadIdx.x >> 6] = s;
  __syncthreads();
  if (threadIdx.x == 0) atomicAdd(out, red[0] + red[1] + red[2] + red[3]);
}

// ---------------- weight ternarization: q = clip(round(w/scale), -1, 1) ----------------
__global__ void quantw_kernel(const float* __restrict__ w, size_t n4,
                              const double* __restrict__ sum, double invcnt,
                              int8_t* __restrict__ q) {
  const float scale = (float)fmax(sum[0] * invcnt, (double)EPSQ);
  const float4* w4 = (const float4*)w;
  char4* q4 = (char4*)q;
  for (size_t i = blockIdx.x * (size_t)blockDim.x + threadIdx.x; i < n4;
       i += (size_t)gridDim.x * blockDim.x) {
    float4 v = w4[i];
    char4 c;
    c.x = (signed char)fmaxf(-1.f, fminf(1.f, rintf(v.x / scale)));
    c.y = (signed char)fmaxf(-1.f, fminf(1.f, rintf(v.y / scale)));
    c.z = (signed char)fmaxf(-1.f, fminf(1.f, rintf(v.z / scale)));
    c.w = (signed char)fmaxf(-1.f, fminf(1.f, rintf(v.w / scale)));
    q4[i] = c;
  }
}

// ---------------- FWHT: one wave per token, H_N = H_E(regs) (x) H_64(lanes) ----------------
template <int LOGN, bool HALF_IN>
__global__ void __launch_bounds__(256) fwht_quant_kernel(const void* __restrict__ Xv,
                                                         int8_t* __restrict__ Q,
                                                         float* __restrict__ invs) {
  constexpr int N = 1 << LOGN;
  constexpr int E = N / 64;                     // 32 (2048) or 64 (4096) regs/lane
  const int lane = threadIdx.x & 63;
  const size_t t = (size_t)blockIdx.x * 4 + (threadIdx.x >> 6);

  float r[E];
  if constexpr (HALF_IN) {
    const int4* xp = (const int4*)((const __half*)Xv + t * (size_t)N + lane * E);
    #pragma unroll
    for (int u = 0; u < E / 8; ++u) {
      alignas(16) __half hb[8];
      *(int4*)hb = xp[u];
      #pragma unroll
      for (int j = 0; j < 8; ++j) r[u * 8 + j] = __half2float(hb[j]);
    }
  } else {
    const float4* xp = (const float4*)((const float*)Xv + t * (size_t)N + lane * E);
    #pragma unroll
    for (int u = 0; u < E / 4; ++u) {
      float4 v = xp[u];
      r[u * 4 + 0] = v.x; r[u * 4 + 1] = v.y; r[u * 4 + 2] = v.z; r[u * 4 + 3] = v.w;
    }
  }

  #pragma unroll
  for (int m = 1; m < E; m <<= 1) {
    #pragma unroll
    for (int e = 0; e < E; ++e) {
      if (!(e & m)) {
        float a = r[e], b = r[e | m];
        r[e] = a + b;
        r[e | m] = a - b;
      }
    }
  }
  #pragma unroll
  for (int m = 1; m < 64; m <<= 1) {
    const float sgn = (lane & m) ? -1.f : 1.f;
    #pragma unroll
    for (int e = 0; e < E; ++e) {
      float w = __shfl_xor(r[e], m, 64);
      r[e] = fmaf(r[e], sgn, w);
    }
  }

  float mx = 0.f;
  #pragma unroll
  for (int e = 0; e < E; ++e) mx = fmaxf(mx, fabsf(r[e]));
  #pragma unroll
  for (int m = 1; m < 64; m <<= 1) mx = fmaxf(mx, __shfl_xor(mx, m, 64));

  constexpr float c = (LOGN == 11) ? 0.022097086912079608f : 0.015625f;  // 1/sqrt(N)
  mx = fmaxf(mx * c, EPSQ);
  const float sc = 127.0f * c / mx;
  if (lane == 0) invs[t] = mx * (1.0f / 127.0f);

  alignas(16) int8_t qv[E];
  #pragma unroll
  for (int e = 0; e < E; ++e) {
    float q = rintf(r[e] * sc);
    q = fmaxf(-127.f, fminf(127.f, q));
    qv[e] = (int8_t)q;
  }
  int8_t* qp = Q + t * (size_t)N + lane * E;
  #pragma unroll
  for (int u = 0; u < E / 16; ++u) ((int4*)qp)[u] = ((const int4*)qv)[u];
}

// ---------------- int8 GEMM, 256x256 tile, 8-phase schedule (T1+T2+T3/T4+T5) --------
// 8 waves (2M x 4N), each wave a 128x64 output via 8x4 mfma_i32_16x16x64_i8 frags.
// BK = 128 bytes/K-tile; 2 K-tiles per loop iteration.
// R2 schedule (unmeasured in R2 due to container-level infra failure; re-run):
//  (a) NO blanket lgkmcnt(0): compiler emits fine-grained lgkm waits per MFMA
//      operand, so the LDS drain hides under the MFMA pipe. WAR stays safe:
//      every ds_read feeds a same-phase MFMA, so reads complete before the last
//      MFMA issues -> before the closing barrier -> before next-phase stage
//      writes can land.
//  (b) Stage slots packed for 4-phase vmcnt margin: buf0.B last read ph2,
//      buf0.A ph3, buf1.B ph6, buf1.A ph7  =>  stage B' at ph3 (2 halves),
//      A' at ph4, B'' at ph7, A'' at ph8. Gates: vmcnt(8) at ph4/ph8 with 16
//      loads outstanding (waits the 8 oldest = buffer being opened); newest
//      required load is always 4 phases old -> no HBM-latency stall.
template <bool RELU2, typename TOUT>
__global__ __launch_bounds__(512, 2)
void gemm_i8_8ph(const int8_t* __restrict__ A, const int8_t* __restrict__ B,
                 TOUT* __restrict__ C, const float* __restrict__ invs,
                 const double* __restrict__ wsum, double invcnt,
                 int N, int K) {
  __shared__ int8_t As[2 * 2 * 128 * 128];
  __shared__ int8_t Bs[2 * 2 * 128 * 128];

  // T1: XCD-aware chunked swizzle (nwg % 8 == 0 for all launches here)
  const int GX = N >> 8;
  const int nwg = gridDim.x;
  int wg = blockIdx.x;
  wg = (wg & 7) * (nwg >> 3) + (wg >> 3);
  const int bx = wg % GX;
  const int by = wg / GX;
  const int m0 = by * 256, n0 = bx * 256;

  const int t = threadIdx.x;
  const int lane = t & 63;
  const int wave = t >> 6;
  const int wr = wave >> 2;  // 0..1 (M)
  const int wc = wave & 3;   // 0..3 (N)

  // ---- staging: global source pre-swizzled, LDS dest linear (rule: both-or-neither)
  const int row0 = t >> 3;                                  // 0..63
  const int colsw = ((t & 7) * 16) ^ ((row0 & 7) << 4);
  const int8_t* gA0 = A + (size_t)(m0 + row0) * K + colsw;
  const int8_t* gA1 = gA0 + (size_t)128 * K;
  const int8_t* gB0 = B + (size_t)(n0 + row0) * K + colsw;
  const int8_t* gB1 = gB0 + (size_t)128 * K;
  const size_t rstep = (size_t)64 * K;

  auto SA = [&](int bf, int hf, int kt) {
    const int8_t* g = (hf ? gA1 : gA0) + (size_t)kt * 128;
    int8_t* l = As + bf * 32768 + hf * 16384 + t * 16;
    async_ld16(g, l);
    async_ld16(g + rstep, l + 8192);
  };
  auto SB = [&](int bf, int hf, int kt) {
    const int8_t* g = (hf ? gB1 : gB0) + (size_t)kt * 128;
    int8_t* l = Bs + bf * 32768 + hf * 16384 + t * 16;
    async_ld16(g, l);
    async_ld16(g + rstep, l + 8192);
  };

  // ---- swizzled ds_read addressing: row&7 == lane&7 for every fragment row
  const int csw0 = ((lane >> 4) * 16) ^ ((lane & 7) << 4);        // kk = 0
  const int csw1 = (64 + (lane >> 4) * 16) ^ ((lane & 7) << 4);   // kk = 1
  const int8_t* pA0 = As + wr * 16384 + (lane & 15) * 128;
  const int8_t* pB0 = Bs + (wc >> 1) * 16384 + ((wc & 1) * 64 + (lane & 15)) * 128;

  v4i acc[8][4] = {};
  v4i a[4][2], b[4][2];

  auto RDA = [&](int bf, int m4) {
    const int8_t* p = pA0 + bf * 32768 + m4 * 8192;
    #pragma unroll
    for (int mt = 0; mt < 4; ++mt) {
      a[mt][0] = *(const v4i*)(p + mt * 2048 + csw0);
      a[mt][1] = *(const v4i*)(p + mt * 2048 + csw1);
    }
  };
  auto RDB = [&](int bf, int n2) {
    const int8_t* p = pB0 + bf * 32768 + n2 * 4096;
    #pragma unroll
    for (int nt = 0; nt < 2; ++nt) {
      b[n2 * 2 + nt][0] = *(const v4i*)(p + nt * 2048 + csw0);
      b[n2 * 2 + nt][1] = *(const v4i*)(p + nt * 2048 + csw1);
    }
  };
  auto MM = [&](int m4, int n2) {   // T5: setprio around the 16-MFMA cluster
    __builtin_amdgcn_s_setprio(1);
    #pragma unroll
    for (int mt = 0; mt < 4; ++mt)
      #pragma unroll
      for (int nt = 0; nt < 2; ++nt) {
        v4i* c = &acc[m4 * 4 + mt][n2 * 2 + nt];
        *c = __builtin_amdgcn_mfma_i32_16x16x64_i8(a[mt][0], b[n2 * 2 + nt][0], *c, 0, 0, 0);
        *c = __builtin_amdgcn_mfma_i32_16x16x64_i8(a[mt][1], b[n2 * 2 + nt][1], *c, 0, 0, 0);
      }
    __builtin_amdgcn_s_setprio(0);
  };

  const int NIT = K >> 8;  // 2 K-tiles (256 bytes of K) per iteration; NIT >= 8 here

  // prologue: stage tile0 -> buf0 (8 loads) then tile1 -> buf1 (8 loads);
  // vmcnt(8) waits the 8 oldest (= buf0), leaving buf1's 8 in flight.
  SB(0, 0, 0); SB(0, 1, 0); SA(0, 0, 0); SA(0, 1, 0);
  SB(1, 0, 1); SB(1, 1, 1); SA(1, 0, 1); SA(1, 1, 1);
  VMC(8);
  BAR();

  for (int it = 0; it < NIT; ++it) {
    const int kt2 = 2 * it + 2, kt3 = 2 * it + 3;
    const bool more = it < NIT - 1;

    // ph1: buf0 reads A(mt0-3) + B(nt0-1)
    RDA(0, 0); RDB(0, 0);
    BAR(); MM(0, 0); BAR();

    // ph2: buf0 B(nt2-3) (last buf0.B read)
    RDB(0, 1);
    BAR(); MM(0, 1); BAR();

    // ph3: buf0 A(mt4-7) (last buf0.A read); stage buf0'.B (both halves, tile kt2)
    RDA(0, 1);
    if (more) { SB(0, 0, kt2); SB(0, 1, kt2); }
    BAR(); MM(1, 0); BAR();

    // ph4: stage buf0'.A (both halves); gate: buf1 (staged prev ph7/ph8) landed
    if (more) { SA(0, 0, kt2); SA(0, 1, kt2); VMC(8); } else { VMC(0); }
    BAR(); MM(1, 1); BAR();

    // ph5: buf1 reads A(mt0-3) + B(nt0-1)
    RDA(1, 0); RDB(1, 0);
    BAR(); MM(0, 0); BAR();

    // ph6: buf1 B(nt2-3) (last buf1.B read)
    RDB(1, 1);
    BAR(); MM(0, 1); BAR();

    // ph7: buf1 A(mt4-7) (last buf1.A read); stage buf1''.B (tile kt3)
    RDA(1, 1);
    if (more) { SB(1, 0, kt3); SB(1, 1, kt3); }
    BAR(); MM(1, 0); BAR();

    // ph8: stage buf1''.A; gate: buf0' (staged ph3/ph4) landed for next ph1
    if (more) { SA(1, 0, kt3); SA(1, 1, kt3); VMC(8); }
    BAR(); MM(1, 1); BAR();
  }

  // ---- epilogue: C/D layout (16x16): col = lane&15, row = (lane>>4)*4 + reg
  const float wscale = (float)fmax(wsum[0] * invcnt, (double)EPSQ);
  const int crow_base = m0 + wr * 128 + (lane >> 4) * 4;
  const int ccol_base = n0 + wc * 64 + (lane & 15);
  #pragma unroll
  for (int mt = 0; mt < 8; ++mt) {
    const int trow = crow_base + mt * 16;
    float fr[4];
    #pragma unroll
    for (int r = 0; r < 4; ++r) fr[r] = wscale * invs[trow + r];
    #pragma unroll
    for (int nt = 0; nt < 4; ++nt) {
      const int col = ccol_base + nt * 16;
      #pragma unroll
      for (int r = 0; r < 4; ++r) {
        float v = (float)acc[mt][nt][r] * fr[r];
        if (RELU2) v = v > 0.f ? v * v : 0.f;
        if constexpr (sizeof(TOUT) == 2)
          C[(size_t)(trow + r) * N + col] = __float2half(v);
        else
          C[(size_t)(trow + r) * N + col] = v;
      }
    }
  }
}

extern "C" void kernel_launch(void* const* d_in, const int* in_sizes, int n_in,
                              void* d_out, int out_size, void* d_ws, size_t ws_size,
                              hipStream_t stream) {
  const float* x      = (const float*)d_in[0];   // (4,4096,2048)
  const float* w_up   = (const float*)d_in[1];   // (4096,2048)
  const float* w_down = (const float*)d_in[2];   // (2048,4096)
  float* out = (float*)d_out;

  const int T = in_sizes[0] / HIDDEN;            // 16384 tokens
  const size_t WN = (size_t)INTER * HIDDEN;      // 8388608 weights per matrix

  char* ws = (char*)d_ws;
  double* sums   = (double*)ws;                                   // [2]
  float* invs1   = (float*)(ws + 256);                            // [T]
  float* invs2   = (float*)(ws + 256 + 65536);                    // [T]
  int8_t* wq_up  = (int8_t*)(ws + 131328);                        // 8 MB
  int8_t* wq_dn  = wq_up + WN;                                    // 8 MB
  int8_t* a8_1   = wq_dn + WN;                                    // T*2048
  int8_t* a8_2   = a8_1 + (size_t)T * HIDDEN;                     // T*4096
  __half* h      = (__half*)(a8_2 + (size_t)T * INTER);           // T*4096 fp16

  const double invcnt = 1.0 / (double)WN;

  hipMemsetAsync(sums, 0, 256, stream);
  absmean_kernel<<<1024, 256, 0, stream>>>(w_up, WN / 4, sums + 0);
  absmean_kernel<<<1024, 256, 0, stream>>>(w_down, WN / 4, sums + 1);
  quantw_kernel<<<2048, 256, 0, stream>>>(w_up, WN / 4, sums + 0, invcnt, wq_up);
  quantw_kernel<<<2048, 256, 0, stream>>>(w_down, WN / 4, sums + 1, invcnt, wq_dn);

  fwht_quant_kernel<11, false><<<T / 4, 256, 0, stream>>>(x, a8_1, invs1);
  gemm_i8_8ph<true, __half><<<(T / 256) * (INTER / 256), 512, 0, stream>>>(
      a8_1, wq_up, h, invs1, sums + 0, invcnt, INTER, HIDDEN);
  fwht_quant_kernel<12, true><<<T / 4, 256, 0, stream>>>(h, a8_2, invs2);
  gemm_i8_8ph<false, float><<<(T / 256) * (HIDDEN / 256), 512, 0, stream>>>(
      a8_2, wq_dn, out, invs2, sums + 1, invcnt, HIDDEN, INTER);
}